// Round 7
// baseline (288.875 us; speedup 1.0000x reference)
//
#include <hip/hip_runtime.h>
#include <hip/hip_bf16.h>
#include <stdint.h>

#define CDIM 768
#define HDIM 48

typedef float  f32x4  __attribute__((ext_vector_type(4)));
typedef short  bf16x8 __attribute__((ext_vector_type(8)));
typedef unsigned short u16x4 __attribute__((ext_vector_type(4)));

__device__ __forceinline__ unsigned short f2bf(float x) {
    __hip_bfloat16 h = __float2bfloat16(x);   // HW RNE convert
    return *reinterpret_cast<unsigned short*>(&h);
}
#define SB0() __builtin_amdgcn_sched_barrier(0)

__device__ __forceinline__ void gload_lds16(const void* g, void* l) {
    __builtin_amdgcn_global_load_lds(
        (const __attribute__((address_space(1))) unsigned int*)g,
        (__attribute__((address_space(3))) unsigned int*)l, 16, 0, 0);
}

// ---------------- prep: pack weights into MFMA fragment order ----------------
// (unchanged — verified correct since R1)
__global__ __launch_bounds__(256) void prep_kernel(
    const float* __restrict__ W1, const float* __restrict__ b1,
    const float* __restrict__ W2,
    const float* __restrict__ gamma, const float* __restrict__ beta,
    unsigned short* __restrict__ w1p, unsigned short* __restrict__ w2p,
    float* __restrict__ b1p, float* __restrict__ cs1)
{
    const int blk = blockIdx.x, tid = threadIdx.x;
    const int l = tid & 63;
    if (blk < 18) {                       // 72 W1 frags, 4/block
        const int fid = blk * 4 + (tid >> 6);
        const int kt = fid / 3, nt = fid % 3;
        const int k0 = kt * 32 + 8 * (l >> 4);
        const int n  = nt * 16 + (l & 15);
        bf16x8 v;
        #pragma unroll
        for (int b = 0; b < 8; ++b) {
            const int k = k0 + b;
            v[b] = (short)f2bf(gamma[k] * W1[k * HDIM + n]);
        }
        *reinterpret_cast<bf16x8*>(w1p + (size_t)(fid * 64 + l) * 8) = v;
    } else if (blk < 42) {                // 96 W2 frags, 4/block
        const int fid = (blk - 18) * 4 + (tid >> 6);
        const int kt = fid / 48, nt = fid % 48;
        const int k0 = kt * 32 + 8 * (l >> 4);
        const int n  = nt * 16 + (l & 15);
        bf16x8 v;
        #pragma unroll
        for (int b = 0; b < 8; ++b) {
            const int k = k0 + b;
            const float w = (k < HDIM) ? W2[k * CDIM + n] : 0.0f;
            v[b] = (short)f2bf(w);
        }
        *reinterpret_cast<bf16x8*>(w2p + (size_t)(fid * 64 + l) * 8) = v;
    } else {                              // b1p / cs1 reductions
        const int j = tid >> 2, p = tid & 3;
        float sb = 0.f, sg = 0.f;
        if (j < HDIM) {
            for (int c = p * 192; c < (p + 1) * 192; ++c) {
                const float w = W1[c * HDIM + j];
                sb += beta[c]  * w;
                sg += gamma[c] * w;
            }
        }
        sb += __shfl_xor(sb, 1); sb += __shfl_xor(sb, 2);
        sg += __shfl_xor(sg, 1); sg += __shfl_xor(sg, 2);
        if (p == 0 && j < HDIM) { b1p[j] = b1[j] + sb; cs1[j] = sg; }
    }
}

// ---------------- main fused kernel ----------------
// BARRIER-FREE per-wave pipeline: each wave stages its OWN 16 rows into its
// OWN 2x2KB LDS double-buffer via global_load_lds; no cross-wave sharing of x
// => no s_barrier in the whole K-loop. Self-paced on counted vmcnt:
// pair(cc) = [w(cc):3 loads, x(cc):2 DMA]; steady-state invariant entering
// iter cc: FIFO = [pair cc, pair cc+1] (10 ops) -> vmcnt(5) keeps exactly the
// 5 youngest = pair(cc+1). Position-independent (older strays retire first).
// LDS rows XOR-swizzled via pre-swizzled DMA SOURCE (dest stays lane-linear),
// same involution applied on ds_read. hid tile reuses the wave's buffer.
__global__ __launch_bounds__(256, 4) void mlp_kernel(
    const float* __restrict__ x,
    const float* __restrict__ b2g,
    const unsigned short* __restrict__ w1p,
    const unsigned short* __restrict__ w2p,
    const float* __restrict__ b1p,
    const float* __restrict__ cs1,
    float* __restrict__ out)
{
    __shared__ __align__(16) float lds_x[4][1024];   // per-wave 4 KB (2x2KB dbuf; later hid)
    __shared__ __align__(16) float lds_b2[CDIM];
    __shared__ __align__(16) float lds_b1[HDIM];
    __shared__ __align__(16) float lds_cs[HDIM];

    const int tid  = threadIdx.x;
    const int w    = tid >> 6;
    const int l    = tid & 63;
    const int lrow = l & 15;
    const int lg   = l >> 4;

    // one-time const staging (before any pipeline issue; sync drains it)
    if (tid < 192)       reinterpret_cast<f32x4*>(lds_b2)[tid]       = reinterpret_cast<const f32x4*>(b2g)[tid];
    else if (tid < 204)  reinterpret_cast<f32x4*>(lds_b1)[tid - 192] = reinterpret_cast<const f32x4*>(b1p)[tid - 192];
    else if (tid < 216)  reinterpret_cast<f32x4*>(lds_cs)[tid - 204] = reinterpret_cast<const f32x4*>(cs1)[tid - 204];
    __syncthreads();

    const bf16x8* __restrict__ w1f = reinterpret_cast<const bf16x8*>(w1p);
    const bf16x8* __restrict__ w2f = reinterpret_cast<const bf16x8*>(w2p);

    const int    tile = blockIdx.x * 4 + w;          // one 16-row tile per wave
    const size_t m0   = (size_t)tile * 16;

    char* const wavebuf = (char*)&lds_x[w][0];
    // pre-swizzled per-lane DMA source offsets: linear LDS byte o=g*1024+l*16
    // holds (row r = o/128, physical col p = o%128); global col c = p ^ ((r&7)<<4)
    int srcoff[2];
    #pragma unroll
    for (int g = 0; g < 2; ++g) {
        const int r = g * 8 + (l >> 3);
        srcoff[g] = r * 3072 + (((l & 7) * 16) ^ ((r & 7) << 4));
    }
    const char* const xg = (const char*)x + m0 * 3072;

    // prologue: pairs 0,1  ([w:3, x:2] each)
    bf16x8 wq[2][3];
    #pragma unroll
    for (int i = 0; i < 2; ++i) {
        #pragma unroll
        for (int q = 0; q < 3; ++q) wq[i][q] = w1f[(i * 3 + q) * 64 + l];
        gload_lds16(xg + i * 128 + srcoff[0], wavebuf + i * 2048 + l * 16);
        gload_lds16(xg + i * 128 + srcoff[1], wavebuf + i * 2048 + 1024 + l * 16);
    }
    SB0();

    const int rowb = lrow * 128;
    const int rx   = (lrow & 7) << 4;

    f32x4 acc1[3];
    #pragma unroll
    for (int nt = 0; nt < 3; ++nt) { acc1[nt][0]=0.f; acc1[nt][1]=0.f; acc1[nt][2]=0.f; acc1[nt][3]=0.f; }
    float rsum = 0.f, rsq = 0.f;

    #pragma unroll
    for (int cc = 0; cc < 24; ++cc) {
        // retire pair(cc): w regs valid + x chunk landed in LDS
        if (cc < 23) asm volatile("s_waitcnt vmcnt(5)" ::: "memory");
        else         asm volatile("s_waitcnt vmcnt(0)" ::: "memory");
        // SSA-capture pair cc before its slots are re-issued
        const bf16x8 wv0 = wq[cc & 1][0];
        const bf16x8 wv1 = wq[cc & 1][1];
        const bf16x8 wv2 = wq[cc & 1][2];
        const char* bb = wavebuf + (cc & 1) * 2048;
        const f32x4 xa = *reinterpret_cast<const f32x4*>(bb + rowb + ((lg * 32     ) ^ rx));
        const f32x4 xb = *reinterpret_cast<const f32x4*>(bb + rowb + ((lg * 32 + 16) ^ rx));
        asm volatile("s_waitcnt lgkmcnt(0)" ::: "memory");   // reads done -> buffer reusable
        SB0();
        // issue pair(cc+2) into the just-freed slot/buffer
        if (cc + 2 < 24) {
            #pragma unroll
            for (int q = 0; q < 3; ++q)
                wq[cc & 1][q] = w1f[((cc + 2) * 3 + q) * 64 + l];
            gload_lds16(xg + (cc + 2) * 128 + srcoff[0], wavebuf + (cc & 1) * 2048 + l * 16);
            gload_lds16(xg + (cc + 2) * 128 + srcoff[1], wavebuf + (cc & 1) * 2048 + 1024 + l * 16);
        }
        SB0();
        // compute ktile cc + row stats
        bf16x8 bf;
        #pragma unroll
        for (int b = 0; b < 4; ++b) {
            rsum += xa[b]; rsq += xa[b] * xa[b];
            rsum += xb[b]; rsq += xb[b] * xb[b];
            bf[b]     = (short)f2bf(xa[b]);
            bf[b + 4] = (short)f2bf(xb[b]);
        }
        acc1[0] = __builtin_amdgcn_mfma_f32_16x16x32_bf16(wv0, bf, acc1[0], 0, 0, 0);
        acc1[1] = __builtin_amdgcn_mfma_f32_16x16x32_bf16(wv1, bf, acc1[1], 0, 0, 0);
        acc1[2] = __builtin_amdgcn_mfma_f32_16x16x32_bf16(wv2, bf, acc1[2], 0, 0, 0);
    }

    rsum += __shfl_xor(rsum, 16); rsum += __shfl_xor(rsum, 32);
    rsq  += __shfl_xor(rsq , 16); rsq  += __shfl_xor(rsq , 32);
    const float mu   = rsum * (1.f / 768.f);
    const float var  = rsq * (1.f / 768.f) - mu * mu;
    const float rstd = rsqrtf(var + 1e-5f);

    // hid tile [16][72] bf16 reuses wavebuf (x-staging done; same-wave ds order)
    unsigned short* const hid = (unsigned short*)wavebuf;
    // zero k-pad cols 48..63
    *reinterpret_cast<unsigned long long*>(hid + (l >> 2) * 72 + 48 + (l & 3) * 4) = 0ull;
    // LN fixup + bias + QuickGELU -> hid
    #pragma unroll
    for (int nt = 0; nt < 3; ++nt) {
        const int c4 = nt * 16 + 4 * lg;
        const f32x4 bb = *reinterpret_cast<const f32x4*>(&lds_b1[c4]);
        const f32x4 cs = *reinterpret_cast<const f32x4*>(&lds_cs[c4]);
        u16x4 pk;
        #pragma unroll
        for (int r = 0; r < 4; ++r) {
            const float h = rstd * (acc1[nt][r] - mu * cs[r]) + bb[r];
            const float g = h / (1.f + __expf(-1.702f * h));
            pk[r] = f2bf(g);
        }
        *reinterpret_cast<u16x4*>(hid + lrow * 72 + c4) = pk;
    }
    const bf16x8 a2_0 = *reinterpret_cast<const bf16x8*>(hid + lrow * 72 + 8 * lg);
    const bf16x8 a2_1 = *reinterpret_cast<const bf16x8*>(hid + lrow * 72 + 8 * lg + 32);

    const float* __restrict__ xres = x   + (m0 + lrow) * CDIM;
    float* __restrict__       ores = out + (m0 + lrow) * CDIM;

    // ===== GEMM2 (R2-verbatim): 6 chunks x 8 ctiles, residual issued first =====
    #pragma unroll 1
    for (int ch = 0; ch < 6; ++ch) {
        f32x4 res[8];
        #pragma unroll
        for (int n8 = 0; n8 < 8; ++n8)
            res[n8] = *reinterpret_cast<const f32x4*>(xres + (ch * 8 + n8) * 16 + 4 * lg);
        f32x4 acc2[8];
        #pragma unroll
        for (int n8 = 0; n8 < 8; ++n8) { acc2[n8][0]=0.f; acc2[n8][1]=0.f; acc2[n8][2]=0.f; acc2[n8][3]=0.f; }
        #pragma unroll
        for (int n8 = 0; n8 < 8; ++n8) {
            const int ct = ch * 8 + n8;
            acc2[n8] = __builtin_amdgcn_mfma_f32_16x16x32_bf16(w2f[ct * 64 + l],        a2_0, acc2[n8], 0, 0, 0);
            acc2[n8] = __builtin_amdgcn_mfma_f32_16x16x32_bf16(w2f[(48 + ct) * 64 + l], a2_1, acc2[n8], 0, 0, 0);
        }
        #pragma unroll
        for (int n8 = 0; n8 < 8; ++n8) {
            const int c4 = (ch * 8 + n8) * 16 + 4 * lg;
            const f32x4 bb = *reinterpret_cast<const f32x4*>(&lds_b2[c4]);
            f32x4 o;
            #pragma unroll
            for (int r = 0; r < 4; ++r) o[r] = acc2[n8][r] + bb[r] + res[n8][r];
            *reinterpret_cast<f32x4*>(ores + c4) = o;
        }
    }
}

extern "C" void kernel_launch(void* const* d_in, const int* in_sizes, int n_in,
                              void* d_out, int out_size, void* d_ws, size_t ws_size,
                              hipStream_t stream)
{
    const float* x     = (const float*)d_in[0];
    const float* W1    = (const float*)d_in[1];
    const float* b1    = (const float*)d_in[2];
    const float* W2    = (const float*)d_in[3];
    const float* b2    = (const float*)d_in[4];
    const float* gamma = (const float*)d_in[5];
    const float* beta  = (const float*)d_in[6];
    float* out = (float*)d_out;

    unsigned short* w1p = (unsigned short*)d_ws;     // 72 frags * 512 B  = 73728 B
    unsigned short* w2p = w1p + 24 * 3 * 64 * 8;     // 96 frags * 512 B  = 98304 B
    float* b1p = (float*)(w2p + 2 * 48 * 64 * 8);    // 48 f32
    float* cs1 = b1p + 64;                           // 48 f32 (16B-aligned gap)

    const int M = in_sizes[0] / CDIM;   // 131072 rows
    const int blocks = M / 64;          // 2048 blocks x 4 waves = 8192 tiles

    prep_kernel<<<dim3(43), dim3(256), 0, stream>>>(W1, b1, W2, gamma, beta, w1p, w2p, b1p, cs1);
    mlp_kernel<<<dim3(blocks), dim3(256), 0, stream>>>(x, b2, w1p, w2p, b1p, cs1, out);
}

// Round 8
// 275.026 us; speedup vs baseline: 1.0504x; 1.0504x over previous
//
#include <hip/hip_runtime.h>
#include <hip/hip_bf16.h>
#include <stdint.h>

#define CDIM 768
#define HDIM 48

typedef float  f32x4  __attribute__((ext_vector_type(4)));
typedef short  bf16x8 __attribute__((ext_vector_type(8)));
typedef unsigned short u16x4 __attribute__((ext_vector_type(4)));

__device__ __forceinline__ unsigned short f2bf(float x) {
    __hip_bfloat16 h = __float2bfloat16(x);   // HW RNE convert
    return *reinterpret_cast<unsigned short*>(&h);
}
#define SB0() __builtin_amdgcn_sched_barrier(0)

__device__ __forceinline__ void gload_lds16(const void* g, void* l) {
    __builtin_amdgcn_global_load_lds(
        (const __attribute__((address_space(1))) unsigned int*)g,
        (__attribute__((address_space(3))) unsigned int*)l, 16, 0, 0);
}

// ---------------- prep: pack weights into MFMA fragment order ----------------
// (unchanged — verified correct since R1)
__global__ __launch_bounds__(256) void prep_kernel(
    const float* __restrict__ W1, const float* __restrict__ b1,
    const float* __restrict__ W2,
    const float* __restrict__ gamma, const float* __restrict__ beta,
    unsigned short* __restrict__ w1p, unsigned short* __restrict__ w2p,
    float* __restrict__ b1p, float* __restrict__ cs1)
{
    const int blk = blockIdx.x, tid = threadIdx.x;
    const int l = tid & 63;
    if (blk < 18) {                       // 72 W1 frags, 4/block
        const int fid = blk * 4 + (tid >> 6);
        const int kt = fid / 3, nt = fid % 3;
        const int k0 = kt * 32 + 8 * (l >> 4);
        const int n  = nt * 16 + (l & 15);
        bf16x8 v;
        #pragma unroll
        for (int b = 0; b < 8; ++b) {
            const int k = k0 + b;
            v[b] = (short)f2bf(gamma[k] * W1[k * HDIM + n]);
        }
        *reinterpret_cast<bf16x8*>(w1p + (size_t)(fid * 64 + l) * 8) = v;
    } else if (blk < 42) {                // 96 W2 frags, 4/block
        const int fid = (blk - 18) * 4 + (tid >> 6);
        const int kt = fid / 48, nt = fid % 48;
        const int k0 = kt * 32 + 8 * (l >> 4);
        const int n  = nt * 16 + (l & 15);
        bf16x8 v;
        #pragma unroll
        for (int b = 0; b < 8; ++b) {
            const int k = k0 + b;
            const float w = (k < HDIM) ? W2[k * CDIM + n] : 0.0f;
            v[b] = (short)f2bf(w);
        }
        *reinterpret_cast<bf16x8*>(w2p + (size_t)(fid * 64 + l) * 8) = v;
    } else {                              // b1p / cs1 reductions
        const int j = tid >> 2, p = tid & 3;
        float sb = 0.f, sg = 0.f;
        if (j < HDIM) {
            for (int c = p * 192; c < (p + 1) * 192; ++c) {
                const float w = W1[c * HDIM + j];
                sb += beta[c]  * w;
                sg += gamma[c] * w;
            }
        }
        sb += __shfl_xor(sb, 1); sb += __shfl_xor(sb, 2);
        sg += __shfl_xor(sg, 1); sg += __shfl_xor(sg, 2);
        if (p == 0 && j < HDIM) { b1p[j] = b1[j] + sb; cs1[j] = sg; }
    }
}

// ---------------- main fused kernel ----------------
// Barrier-free per-wave DMA pipeline with 512 B-contiguous runs:
// chunk = 16 rows x 128 cols fp32 (8 KB); 8 gload_lds per chunk, each 1 KB
// covering 2 rows x 512 B contiguous (permuted 16B granules = same byte set).
// Double-buffered (16 KB/wave). Distance-matched pairs [w(cc+2):12, x(cc+2):8],
// steady-state vmcnt(20) = keep exactly pair(cc+1). LDS granule-XOR swizzle
// (g ^= row&7) applied on DMA SOURCE and on ds_read (linear dest, G21).
__global__ __launch_bounds__(256, 2) void mlp_kernel(
    const float* __restrict__ x,
    const float* __restrict__ b2g,
    const unsigned short* __restrict__ w1p,
    const unsigned short* __restrict__ w2p,
    const float* __restrict__ b1p,
    const float* __restrict__ cs1,
    float* __restrict__ out)
{
    __shared__ __align__(16) float lds_x[4][4096];   // per-wave 16 KB (2 x 8 KB dbuf; later hid)
    __shared__ __align__(16) float lds_b2[CDIM];
    __shared__ __align__(16) float lds_b1[HDIM];
    __shared__ __align__(16) float lds_cs[HDIM];

    const int tid  = threadIdx.x;
    const int w    = tid >> 6;
    const int l    = tid & 63;
    const int lrow = l & 15;
    const int lg   = l >> 4;

    // one-time const staging (drained by the syncthreads -> clean vmcnt baseline)
    if (tid < 192)       reinterpret_cast<f32x4*>(lds_b2)[tid]       = reinterpret_cast<const f32x4*>(b2g)[tid];
    else if (tid < 204)  reinterpret_cast<f32x4*>(lds_b1)[tid - 192] = reinterpret_cast<const f32x4*>(b1p)[tid - 192];
    else if (tid < 216)  reinterpret_cast<f32x4*>(lds_cs)[tid - 204] = reinterpret_cast<const f32x4*>(cs1)[tid - 204];
    __syncthreads();

    const bf16x8* __restrict__ w1f = reinterpret_cast<const bf16x8*>(w1p);
    const bf16x8* __restrict__ w2f = reinterpret_cast<const bf16x8*>(w2p);

    const int    tile = blockIdx.x * 4 + w;          // one 16-row tile per wave
    const size_t m0   = (size_t)tile * 16;

    char* const wavebuf = (char*)&lds_x[w][0];
    const char* const xg = (const char*)x + m0 * 3072;

    // DMA source offsets: instr j covers rows {2j, 2j+(l>>5)}: lane's row
    // r = 2j + (l>>5); phys granule (l&31) holds logical granule (l&31)^(r&7).
    int srcoff[8];
    #pragma unroll
    for (int j = 0; j < 8; ++j) {
        const int r = 2 * j + (l >> 5);
        srcoff[j] = r * 3072 + ((((l & 31) ^ (r & 7))) << 4);
    }

    // prologue: pairs 0,1  ([w:12, x:8] each)
    bf16x8 wq[2][12];
    #pragma unroll
    for (int i = 0; i < 2; ++i) {
        #pragma unroll
        for (int q = 0; q < 12; ++q) wq[i][q] = w1f[(i * 12 + q) * 64 + l];
        #pragma unroll
        for (int j = 0; j < 8; ++j)
            gload_lds16(xg + i * 512 + srcoff[j], wavebuf + i * 8192 + j * 1024);
    }
    SB0();

    const int rowb = lrow * 512;
    const int rx   = (lrow & 7) << 4;

    f32x4 acc1[3];
    #pragma unroll
    for (int nt = 0; nt < 3; ++nt) { acc1[nt][0]=0.f; acc1[nt][1]=0.f; acc1[nt][2]=0.f; acc1[nt][3]=0.f; }
    float rsum = 0.f, rsq = 0.f;

    #pragma unroll
    for (int cc = 0; cc < 6; ++cc) {
        // retire pair(cc); keep pair(cc+1) in flight
        if (cc < 5) asm volatile("s_waitcnt vmcnt(20)" ::: "memory");
        else        asm volatile("s_waitcnt vmcnt(0)" ::: "memory");
        // SSA-capture w(cc) before its slots are re-issued
        bf16x8 wv[12];
        #pragma unroll
        for (int q = 0; q < 12; ++q) wv[q] = wq[cc & 1][q];
        // pull this chunk's row into regs (swizzled ds_read, 8 x b128)
        const char* bb = wavebuf + (cc & 1) * 8192 + rowb;
        f32x4 xr[8];
        #pragma unroll
        for (int ktl = 0; ktl < 4; ++ktl) {
            xr[2*ktl+0] = *reinterpret_cast<const f32x4*>(bb + ((ktl * 128 + lg * 32     ) ^ rx));
            xr[2*ktl+1] = *reinterpret_cast<const f32x4*>(bb + ((ktl * 128 + lg * 32 + 16) ^ rx));
        }
        asm volatile("s_waitcnt lgkmcnt(0)" ::: "memory");   // reads done -> buffer reusable
        SB0();
        // issue pair(cc+2) into the just-freed slot/buffer (w first, x second)
        if (cc + 2 < 6) {
            #pragma unroll
            for (int q = 0; q < 12; ++q)
                wq[cc & 1][q] = w1f[((cc + 2) * 12 + q) * 64 + l];
            #pragma unroll
            for (int j = 0; j < 8; ++j)
                gload_lds16(xg + (cc + 2) * 512 + srcoff[j], wavebuf + (cc & 1) * 8192 + j * 1024);
        }
        SB0();
        // compute chunk cc: 4 ktiles + row stats
        #pragma unroll
        for (int ktl = 0; ktl < 4; ++ktl) {
            const f32x4 xa = xr[2*ktl+0];
            const f32x4 xb = xr[2*ktl+1];
            bf16x8 bf;
            #pragma unroll
            for (int b = 0; b < 4; ++b) {
                rsum += xa[b]; rsq += xa[b] * xa[b];
                rsum += xb[b]; rsq += xb[b] * xb[b];
                bf[b]     = (short)f2bf(xa[b]);
                bf[b + 4] = (short)f2bf(xb[b]);
            }
            acc1[0] = __builtin_amdgcn_mfma_f32_16x16x32_bf16(wv[ktl*3+0], bf, acc1[0], 0, 0, 0);
            acc1[1] = __builtin_amdgcn_mfma_f32_16x16x32_bf16(wv[ktl*3+1], bf, acc1[1], 0, 0, 0);
            acc1[2] = __builtin_amdgcn_mfma_f32_16x16x32_bf16(wv[ktl*3+2], bf, acc1[2], 0, 0, 0);
        }
    }

    rsum += __shfl_xor(rsum, 16); rsum += __shfl_xor(rsum, 32);
    rsq  += __shfl_xor(rsq , 16); rsq  += __shfl_xor(rsq , 32);
    const float mu   = rsum * (1.f / 768.f);
    const float var  = rsq * (1.f / 768.f) - mu * mu;
    const float rstd = rsqrtf(var + 1e-5f);

    // hid tile [16][72] bf16 reuses wavebuf (x fully consumed; same-wave ds order)
    unsigned short* const hid = (unsigned short*)wavebuf;
    *reinterpret_cast<unsigned long long*>(hid + (l >> 2) * 72 + 48 + (l & 3) * 4) = 0ull;
    #pragma unroll
    for (int nt = 0; nt < 3; ++nt) {
        const int c4 = nt * 16 + 4 * lg;
        const f32x4 bb = *reinterpret_cast<const f32x4*>(&lds_b1[c4]);
        const f32x4 cs = *reinterpret_cast<const f32x4*>(&lds_cs[c4]);
        u16x4 pk;
        #pragma unroll
        for (int r = 0; r < 4; ++r) {
            const float h = rstd * (acc1[nt][r] - mu * cs[r]) + bb[r];
            const float g = h / (1.f + __expf(-1.702f * h));
            pk[r] = f2bf(g);
        }
        *reinterpret_cast<u16x4*>(hid + lrow * 72 + c4) = pk;
    }
    const bf16x8 a2_0 = *reinterpret_cast<const bf16x8*>(hid + lrow * 72 + 8 * lg);
    const bf16x8 a2_1 = *reinterpret_cast<const bf16x8*>(hid + lrow * 72 + 8 * lg + 32);

    const float* __restrict__ xres = x   + (m0 + lrow) * CDIM;
    float* __restrict__       ores = out + (m0 + lrow) * CDIM;

    // ===== GEMM2 (R2-verbatim): 6 chunks x 8 ctiles, residual issued first =====
    #pragma unroll 1
    for (int ch = 0; ch < 6; ++ch) {
        f32x4 res[8];
        #pragma unroll
        for (int n8 = 0; n8 < 8; ++n8)
            res[n8] = *reinterpret_cast<const f32x4*>(xres + (ch * 8 + n8) * 16 + 4 * lg);
        f32x4 acc2[8];
        #pragma unroll
        for (int n8 = 0; n8 < 8; ++n8) { acc2[n8][0]=0.f; acc2[n8][1]=0.f; acc2[n8][2]=0.f; acc2[n8][3]=0.f; }
        #pragma unroll
        for (int n8 = 0; n8 < 8; ++n8) {
            const int ct = ch * 8 + n8;
            acc2[n8] = __builtin_amdgcn_mfma_f32_16x16x32_bf16(w2f[ct * 64 + l],        a2_0, acc2[n8], 0, 0, 0);
            acc2[n8] = __builtin_amdgcn_mfma_f32_16x16x32_bf16(w2f[(48 + ct) * 64 + l], a2_1, acc2[n8], 0, 0, 0);
        }
        #pragma unroll
        for (int n8 = 0; n8 < 8; ++n8) {
            const int c4 = (ch * 8 + n8) * 16 + 4 * lg;
            const f32x4 bb = *reinterpret_cast<const f32x4*>(&lds_b2[c4]);
            f32x4 o;
            #pragma unroll
            for (int r = 0; r < 4; ++r) o[r] = acc2[n8][r] + bb[r] + res[n8][r];
            *reinterpret_cast<f32x4*>(ores + c4) = o;
        }
    }
}

extern "C" void kernel_launch(void* const* d_in, const int* in_sizes, int n_in,
                              void* d_out, int out_size, void* d_ws, size_t ws_size,
                              hipStream_t stream)
{
    const float* x     = (const float*)d_in[0];
    const float* W1    = (const float*)d_in[1];
    const float* b1    = (const float*)d_in[2];
    const float* W2    = (const float*)d_in[3];
    const float* b2    = (const float*)d_in[4];
    const float* gamma = (const float*)d_in[5];
    const float* beta  = (const float*)d_in[6];
    float* out = (float*)d_out;

    unsigned short* w1p = (unsigned short*)d_ws;     // 72 frags * 512 B  = 73728 B
    unsigned short* w2p = w1p + 24 * 3 * 64 * 8;     // 96 frags * 512 B  = 98304 B
    float* b1p = (float*)(w2p + 2 * 48 * 64 * 8);    // 48 f32
    float* cs1 = b1p + 64;                           // 48 f32 (16B-aligned gap)

    const int M = in_sizes[0] / CDIM;   // 131072 rows
    const int blocks = M / 64;          // 2048 blocks x 4 waves = 8192 tiles

    prep_kernel<<<dim3(43), dim3(256), 0, stream>>>(W1, b1, W2, gamma, beta, w1p, w2p, b1p, cs1);
    mlp_kernel<<<dim3(blocks), dim3(256), 0, stream>>>(x, b2, w1p, w2p, b1p, cs1, out);
}